// Round 1
// baseline (1020.167 us; speedup 1.0000x reference)
//
#include <hip/hip_runtime.h>

#define EPS 1e-5f
#define KK 27

typedef __bf16 bf16x8 __attribute__((ext_vector_type(8)));
typedef float f32x4 __attribute__((ext_vector_type(4)));

__device__ __forceinline__ unsigned short f2bf(float f) {
    union { float f; unsigned u; } v; v.f = f;
    unsigned r = v.u + 0x7fffu + ((v.u >> 16) & 1u);  // round-to-nearest-even
    return (unsigned short)(r >> 16);
}

__device__ __forceinline__ f32x4 mfma16(bf16x8 a, bf16x8 b, f32x4 c) {
    return __builtin_amdgcn_mfma_f32_16x16x32_bf16(a, b, c, 0, 0, 0);
}

// ---------------- map inversion ----------------
__global__ void fill_i32(int* __restrict__ p, long tot, int val) {
    long i = (long)blockIdx.x * blockDim.x + threadIdx.x;
    if (i < tot) p[i] = val;
}

// dense[k][ko] = ki  (stride n+1 per k; padded entries have ki==n -> skipped,
// so dense[k][n] stays == sentinel n)
__global__ void invert_map(const int* __restrict__ km_in, const int* __restrict__ km_out,
                           int* __restrict__ dense, int M, int nrows) {
    long i = (long)blockIdx.x * blockDim.x + threadIdx.x;
    if (i >= (long)KK * M) return;
    int k = (int)(i / M);
    int ki = km_in[i];
    if (ki < nrows) dense[(long)k * (nrows + 1) + km_out[i]] = ki;
}

// ---------------- weight prep: W[k][ci][co] f32 -> Wt[k][co][ci] bf16 ----------------
__global__ void wt_bf16(const float* __restrict__ W, unsigned short* __restrict__ Wt,
                        int Cin, int Cout) {
    long i = (long)blockIdx.x * blockDim.x + threadIdx.x;
    long tot = (long)KK * Cin * Cout;
    if (i >= tot) return;
    int k  = (int)(i / (Cin * Cout));
    int r  = (int)(i % (Cin * Cout));
    int ci = r / Cout, co = r % Cout;
    Wt[((long)k * Cout + co) * Cin + ci] = f2bf(W[i]);
}

// ---------------- conv1: 1 -> 64 channels, f32, out-centric gather ----------------
__global__ void conv1_kernel(const float* __restrict__ feats, const float* __restrict__ W1,
                             const int* __restrict__ dense, int n, float* __restrict__ out) {
    __shared__ float w1s[KK * 64];
    int tid = threadIdx.y * 64 + threadIdx.x;
    for (int i = tid; i < KK * 64; i += 256) w1s[i] = W1[i];
    __syncthreads();
    int j = blockIdx.x * 4 + threadIdx.y;
    if (j >= n) return;
    int c = threadIdx.x;
    float acc = 0.f;
    for (int k = 0; k < KK; ++k) {
        int r = dense[(long)k * (n + 1) + j];      // wave-uniform (same j across lanes)
        float f = (r < n) ? feats[r] : 0.f;
        acc += f * w1s[k * 64 + c];
    }
    out[(long)j * 64 + c] = acc;
}

// ---------------- per-channel sum / sumsq ----------------
template <int C>
__global__ void stats_kernel(const float* __restrict__ x, long n, float* __restrict__ stats) {
    constexpr int RPB = 256 / C;
    __shared__ float ls[256], lss[256];
    int tid = threadIdx.x;
    int c = tid % C;
    long row = (long)blockIdx.x * RPB + tid / C;
    long stride = (long)gridDim.x * RPB;
    float s = 0.f, ss = 0.f;
    for (; row < n; row += stride) {
        float v = x[row * C + c];
        s += v; ss += v * v;
    }
    ls[tid] = s; lss[tid] = ss;
    __syncthreads();
    if (tid < C) {
        float S = 0.f, SS = 0.f;
        #pragma unroll
        for (int g = 0; g < RPB; ++g) { S += ls[g * C + c]; SS += lss[g * C + c]; }
        atomicAdd(&stats[c], S);
        atomicAdd(&stats[C + c], SS);
    }
}

// ---------------- BN+ReLU -> bf16 (row n written as zeros = the padded row) ----------------
__global__ void bnrelu_bf16_kernel(const float* __restrict__ x, const float* __restrict__ stats,
                                   const float* __restrict__ g, const float* __restrict__ be,
                                   long n, unsigned short* __restrict__ out) {
    long j = (long)blockIdx.x * 4 + threadIdx.y;
    if (j > n) return;
    int c = threadIdx.x;
    unsigned short v16 = 0;
    if (j < n) {
        float mu  = stats[c] / (float)n;
        float var = stats[64 + c] / (float)n - mu * mu;
        float rs  = rsqrtf(var + EPS);
        float v   = g[c] * (x[j * 64 + c] - mu) * rs + be[c];
        v16 = f2bf(v > 0.f ? v : 0.f);
    }
    out[j * 64 + c] = v16;
}

// ---------------- MFMA gather-conv: Cin=64, Cout=NT*16 ----------------
// One wave = one 16-row output tile, all NT column tiles.
// xin: (n+1) x 64 bf16 (row n = zeros). Wt: KK x (NT*16) x 64 bf16. dense: KK x (n+1).
template <int NT>
__global__ __launch_bounds__(256) void conv_mfma(const unsigned short* __restrict__ xin,
                                                 const unsigned short* __restrict__ Wt,
                                                 const int* __restrict__ dense,
                                                 float* __restrict__ out, int n) {
    int wave = threadIdx.x >> 6;
    int lane = threadIdx.x & 63;
    int m16 = lane & 15, quad = lane >> 4;
    long tile = (long)blockIdx.x * 4 + wave;
    long j0 = tile * 16;
    if (j0 >= n) return;
    int jm = (int)j0 + m16;
    if (jm > n) jm = n;                    // sentinel slot: dense[k][n]==n -> zero row
    const int COUT = NT * 16;

    f32x4 acc[NT];
    #pragma unroll
    for (int t = 0; t < NT; ++t) acc[t] = (f32x4){0.f, 0.f, 0.f, 0.f};

    for (int k = 0; k < KK; ++k) {
        int r = dense[(long)k * (n + 1) + jm];
        const bf16x8* arow = (const bf16x8*)(xin + (long)r * 64);
        const unsigned short* wk = Wt + (long)k * COUT * 64 + quad * 8;
        #pragma unroll
        for (int s = 0; s < 2; ++s) {
            bf16x8 a = arow[s * 4 + quad];       // A[m=m16][k = s*32 + quad*8 + j]
            #pragma unroll
            for (int t = 0; t < NT; ++t) {
                // B[n = t*16+m16][k = s*32 + quad*8 + j] from Wt[k][co][ci]
                bf16x8 b = *(const bf16x8*)(wk + (long)(t * 16 + m16) * 64 + s * 32);
                acc[t] = mfma16(a, b, acc[t]);
            }
        }
    }
    long row = j0 + quad * 4;                   // D: col=m16, row=quad*4+reg
    #pragma unroll
    for (int t = 0; t < NT; ++t) {
        #pragma unroll
        for (int r2 = 0; r2 < 4; ++r2) {
            long rr = row + r2;
            if (rr < n) out[rr * COUT + t * 16 + m16] = acc[t][r2];
        }
    }
}

// ---------------- BN+ReLU on x2 fused with segment-max pool (atomicMax on uint, vals>=0) ----------------
__global__ void pool_kernel(const float* __restrict__ x, const float* __restrict__ stats,
                            const float* __restrict__ g, const float* __restrict__ be,
                            const int* __restrict__ seg, long n, unsigned* __restrict__ pooled) {
    long j = (long)blockIdx.x * 4 + threadIdx.y;
    if (j >= n) return;
    int c = threadIdx.x;
    float mu  = stats[c] / (float)n;
    float var = stats[64 + c] / (float)n - mu * mu;
    float rs  = rsqrtf(var + EPS);
    float v   = g[c] * (x[j * 64 + c] - mu) * rs + be[c];
    if (v < 0.f) v = 0.f;
    atomicMax(&pooled[(long)seg[j] * 64 + c], __float_as_uint(v));
}

__global__ void pooled_bf16_kernel(const unsigned* __restrict__ pooled, long np,
                                   unsigned short* __restrict__ out) {
    long j = (long)blockIdx.x * 4 + threadIdx.y;
    if (j > np) return;
    int c = threadIdx.x;
    out[j * 64 + c] = (j == np) ? (unsigned short)0
                                : f2bf(__uint_as_float(pooled[j * 64 + c]));
}

// ---------------- final BN+ReLU, in place on d_out (x3 lives there) ----------------
__global__ void bnrelu_out_kernel(float* __restrict__ x, const float* __restrict__ stats,
                                  const float* __restrict__ g, const float* __restrict__ be,
                                  long n) {
    long j = (long)blockIdx.x * 2 + threadIdx.y;
    if (j >= n) return;
    int c = threadIdx.x;  // 128
    float mu  = stats[c] / (float)n;
    float var = stats[128 + c] / (float)n - mu * mu;
    float rs  = rsqrtf(var + EPS);
    float v   = g[c] * (x[j * 128 + c] - mu) * rs + be[c];
    x[j * 128 + c] = v > 0.f ? v : 0.f;
}

extern "C" void kernel_launch(void* const* d_in, const int* in_sizes, int n_in,
                              void* d_out, int out_size, void* d_ws, size_t ws_size,
                              hipStream_t stream) {
    const float* feats = (const float*)d_in[0];
    const float* W1  = (const float*)d_in[1];
    const float* g1  = (const float*)d_in[3];
    const float* be1 = (const float*)d_in[4];
    const float* W2  = (const float*)d_in[5];
    const float* g2  = (const float*)d_in[7];
    const float* be2 = (const float*)d_in[8];
    const float* W3  = (const float*)d_in[9];
    const float* g3  = (const float*)d_in[11];
    const float* be3 = (const float*)d_in[12];
    const int* km_in   = (const int*)d_in[13];
    const int* km_out  = (const int*)d_in[14];
    const int* pool_seg = (const int*)d_in[15];
    const int* km2_in  = (const int*)d_in[16];
    const int* km2_out = (const int*)d_in[17];

    const int n  = in_sizes[0];           // 160000
    const int M  = in_sizes[13] / KK;
    const int np = out_size / 128;        // N_POOL
    const int M2 = in_sizes[16] / KK;

    // bias terms (b1/b2/b3) are skipped: a per-channel constant shift cancels
    // exactly through training-mode BatchNorm (mean-subtracted, var unchanged).

    char* ws = (char*)d_ws;
    size_t off = 0;
    auto alloc = [&](size_t bytes) -> char* {
        char* p = ws + off;
        off += (bytes + 255) & ~(size_t)255;
        return p;
    };
    int* dense1 = (int*)alloc((size_t)KK * (n + 1) * 4);            // 17.3 MB
    int* dense2 = (int*)alloc((size_t)KK * (np + 1) * 4);           // ~6.7 MB
    unsigned short* W2t = (unsigned short*)alloc((size_t)KK * 64 * 64 * 2);
    unsigned short* W3t = (unsigned short*)alloc((size_t)KK * 128 * 64 * 2);
    float* stats = (float*)alloc(4096);                              // s1@0, s2@128, s3@256
    unsigned short* x1n = (unsigned short*)alloc((size_t)(n + 1) * 64 * 2);   // 20.5 MB
    float* bufA = (float*)alloc((size_t)n * 64 * 4);                 // x1 then x2, 41 MB
    unsigned* pooled = (unsigned*)alloc((size_t)np * 64 * 4);        // ~15.9 MB
    unsigned short* xpn = (unsigned short*)alloc((size_t)(np + 1) * 64 * 2);  // ~7.9 MB
    float* x3 = (float*)d_out;                                       // conv3 out in d_out
    if (off > ws_size) return;  // insufficient workspace -> visible failure

    float* stats1 = stats;
    float* stats2 = stats + 128;
    float* stats3 = stats + 256;

    hipMemsetAsync(stats, 0, 4096, stream);
    hipMemsetAsync(pooled, 0, (size_t)np * 64 * 4, stream);

    // build dense inverse maps
    {
        long t1 = (long)KK * (n + 1);
        fill_i32<<<(int)((t1 + 255) / 256), 256, 0, stream>>>(dense1, t1, n);
        long t2 = (long)KK * (np + 1);
        fill_i32<<<(int)((t2 + 255) / 256), 256, 0, stream>>>(dense2, t2, np);
        long e1 = (long)KK * M;
        invert_map<<<(int)((e1 + 255) / 256), 256, 0, stream>>>(km_in, km_out, dense1, M, n);
        long e2 = (long)KK * M2;
        invert_map<<<(int)((e2 + 255) / 256), 256, 0, stream>>>(km2_in, km2_out, dense2, M2, np);
    }
    // weight transpose+convert
    {
        long t2 = (long)KK * 64 * 64;
        wt_bf16<<<(int)((t2 + 255) / 256), 256, 0, stream>>>(W2, W2t, 64, 64);
        long t3 = (long)KK * 64 * 128;
        wt_bf16<<<(int)((t3 + 255) / 256), 256, 0, stream>>>(W3, W3t, 64, 128);
    }

    dim3 b64x4(64, 4);
    // layer 1
    conv1_kernel<<<(n + 3) / 4, b64x4, 0, stream>>>(feats, W1, dense1, n, bufA);
    stats_kernel<64><<<1024, 256, 0, stream>>>(bufA, n, stats1);
    bnrelu_bf16_kernel<<<(n + 1 + 3) / 4, b64x4, 0, stream>>>(bufA, stats1, g1, be1, n, x1n);
    // layer 2 (MFMA), overwrite bufA with x2
    {
        long tiles = (n + 15) / 16;
        conv_mfma<4><<<(int)((tiles + 3) / 4), 256, 0, stream>>>(x1n, W2t, dense1, bufA, n);
    }
    stats_kernel<64><<<1024, 256, 0, stream>>>(bufA, n, stats2);
    // BN2+ReLU fused into segment-max pool
    pool_kernel<<<(n + 3) / 4, b64x4, 0, stream>>>(bufA, stats2, g2, be2, pool_seg, n, pooled);
    pooled_bf16_kernel<<<(np + 1 + 3) / 4, b64x4, 0, stream>>>(pooled, np, xpn);
    // layer 3 (MFMA) straight into d_out
    {
        long tiles = (np + 15) / 16;
        conv_mfma<8><<<(int)((tiles + 3) / 4), 256, 0, stream>>>(xpn, W3t, dense2, x3, np);
    }
    stats_kernel<128><<<1024, 256, 0, stream>>>(x3, np, stats3);
    bnrelu_out_kernel<<<(np + 1) / 2, dim3(128, 2), 0, stream>>>(x3, stats3, g3, be3, np);
}

// Round 2
// 873.618 us; speedup vs baseline: 1.1677x; 1.1677x over previous
//
#include <hip/hip_runtime.h>

#define EPS 1e-5f
#define KK 27

typedef __bf16 bf16x8 __attribute__((ext_vector_type(8)));
typedef float f32x4 __attribute__((ext_vector_type(4)));

__device__ __forceinline__ unsigned short f2bf(float f) {
    union { float f; unsigned u; } v; v.f = f;
    unsigned r = v.u + 0x7fffu + ((v.u >> 16) & 1u);  // round-to-nearest-even
    return (unsigned short)(r >> 16);
}

__device__ __forceinline__ f32x4 mfma16(bf16x8 a, bf16x8 b, f32x4 c) {
    return __builtin_amdgcn_mfma_f32_16x16x32_bf16(a, b, c, 0, 0, 0);
}

// ---------------- map inversion ----------------
__global__ void fill_i32(int* __restrict__ p, long tot, int val) {
    long i = (long)blockIdx.x * blockDim.x + threadIdx.x;
    if (i < tot) p[i] = val;
}

__global__ void invert_map(const int* __restrict__ km_in, const int* __restrict__ km_out,
                           int* __restrict__ dense, int M, int nrows) {
    long i = (long)blockIdx.x * blockDim.x + threadIdx.x;
    if (i >= (long)KK * M) return;
    int k = (int)(i / M);
    int ki = km_in[i];
    if (ki < nrows) dense[(long)k * (nrows + 1) + km_out[i]] = ki;
}

// ---------------- weight prep: W[k][ci][co] f32 -> Wt[k][co][ci] bf16 ----------------
__global__ void wt_bf16(const float* __restrict__ W, unsigned short* __restrict__ Wt,
                        int Cin, int Cout) {
    long i = (long)blockIdx.x * blockDim.x + threadIdx.x;
    long tot = (long)KK * Cin * Cout;
    if (i >= tot) return;
    int k  = (int)(i / (Cin * Cout));
    int r  = (int)(i % (Cin * Cout));
    int ci = r / Cout, co = r % Cout;
    Wt[((long)k * Cout + co) * Cin + ci] = f2bf(W[i]);
}

// ---------------- conv1: 1 -> 64 channels, f32, out-centric gather ----------------
__global__ void conv1_kernel(const float* __restrict__ feats, const float* __restrict__ W1,
                             const int* __restrict__ dense, int n, float* __restrict__ out) {
    __shared__ float w1s[KK * 64];
    int tid = threadIdx.y * 64 + threadIdx.x;
    for (int i = tid; i < KK * 64; i += 256) w1s[i] = W1[i];
    __syncthreads();
    int j = blockIdx.x * 4 + threadIdx.y;
    if (j >= n) return;
    int c = threadIdx.x;
    // batch all index loads + gathers for MLP
    float f[KK];
    #pragma unroll
    for (int k = 0; k < KK; ++k) {
        int r = dense[(long)k * (n + 1) + j];
        f[k] = (r < n) ? feats[r] : 0.f;
    }
    float acc = 0.f;
    #pragma unroll
    for (int k = 0; k < KK; ++k) acc += f[k] * w1s[k * 64 + c];
    out[(long)j * 64 + c] = acc;
}

// ---------------- per-channel sum / sumsq ----------------
template <int C>
__global__ void stats_kernel(const float* __restrict__ x, long n, float* __restrict__ stats) {
    constexpr int RPB = 256 / C;
    __shared__ float ls[256], lss[256];
    int tid = threadIdx.x;
    int c = tid % C;
    long row = (long)blockIdx.x * RPB + tid / C;
    long stride = (long)gridDim.x * RPB;
    float s = 0.f, ss = 0.f;
    for (; row < n; row += stride) {
        float v = x[row * C + c];
        s += v; ss += v * v;
    }
    ls[tid] = s; lss[tid] = ss;
    __syncthreads();
    if (tid < C) {
        float S = 0.f, SS = 0.f;
        #pragma unroll
        for (int g = 0; g < RPB; ++g) { S += ls[g * C + c]; SS += lss[g * C + c]; }
        atomicAdd(&stats[c], S);
        atomicAdd(&stats[C + c], SS);
    }
}

// ---------------- BN+ReLU -> bf16 (row n written as zeros = the padded row) ----------------
__global__ void bnrelu_bf16_kernel(const float* __restrict__ x, const float* __restrict__ stats,
                                   const float* __restrict__ g, const float* __restrict__ be,
                                   long n, unsigned short* __restrict__ out) {
    long j = (long)blockIdx.x * 4 + threadIdx.y;
    if (j > n) return;
    int c = threadIdx.x;
    unsigned short v16 = 0;
    if (j < n) {
        float mu  = stats[c] / (float)n;
        float var = stats[64 + c] / (float)n - mu * mu;
        float rs  = rsqrtf(var + EPS);
        float v   = g[c] * (x[j * 64 + c] - mu) * rs + be[c];
        v16 = f2bf(v > 0.f ? v : 0.f);
    }
    out[j * 64 + c] = v16;
}

// ---------------- MFMA gather-conv, software-pipelined ----------------
// One wave = 32 output rows (2 M-tiles) x (NT*16) output cols.
// CB column-blocks of NT*16 cols each; COUT = CB*NT*16.
// xin: (n+1) x 64 bf16 (row n zeros). Wt: KK x COUT x 64 bf16. dense: KK x (n+1).
// Pipeline: index loads DI ahead, A-fragment gathers PF ahead, k fully unrolled.
template <int NT, int CB>
__global__ __launch_bounds__(256) void conv_mfma(const unsigned short* __restrict__ xin,
                                                 const unsigned short* __restrict__ Wt,
                                                 const int* __restrict__ dense,
                                                 float* __restrict__ out, int n) {
    constexpr int COUT = NT * 16 * CB;
    constexpr int PF = 3;   // A-fragment prefetch depth
    constexpr int DI = 6;   // index prefetch depth
    int wave = threadIdx.x >> 6;
    int lane = threadIdx.x & 63;
    int m16 = lane & 15, quad = lane >> 4;

    // XCD swizzle: gridDim.x is a multiple of 8; physical block b -> XCD b%8.
    // Give each XCD a contiguous logical range for L2 gather locality.
    int chunk = gridDim.x >> 3;
    int logical = (blockIdx.x & 7) * chunk + (blockIdx.x >> 3);
    long w = (long)logical * 4 + wave;
    long tile = w / CB;
    int colblk = (int)(w % CB);
    long j0 = tile * 32;
    if (j0 >= n) return;

    int jm[2];
    jm[0] = (int)j0 + m16;
    jm[1] = (int)j0 + 16 + m16;
    if (jm[0] > n) jm[0] = n;   // sentinel slot: dense[k][n]==n -> zero row
    if (jm[1] > n) jm[1] = n;

    int idxbuf[DI][2];
    #pragma unroll
    for (int p = 0; p < DI; ++p) {
        const int* dk = dense + (long)p * (n + 1);
        idxbuf[p][0] = dk[jm[0]];
        idxbuf[p][1] = dk[jm[1]];
    }
    bf16x8 abuf[PF][2][2];
    #pragma unroll
    for (int p = 0; p < PF; ++p) {
        #pragma unroll
        for (int t2 = 0; t2 < 2; ++t2) {
            const bf16x8* ar = (const bf16x8*)(xin + (long)idxbuf[p][t2] * 64);
            abuf[p][t2][0] = ar[quad];
            abuf[p][t2][1] = ar[4 + quad];
        }
    }

    f32x4 acc[2][NT];
    #pragma unroll
    for (int t2 = 0; t2 < 2; ++t2)
        #pragma unroll
        for (int t = 0; t < NT; ++t) acc[t2][t] = (f32x4){0.f, 0.f, 0.f, 0.f};

    const unsigned short* wbase = Wt + (long)(colblk * NT * 16) * 64 + quad * 8;

    #pragma unroll
    for (int k = 0; k < KK; ++k) {
        bf16x8 a[2][2];
        #pragma unroll
        for (int t2 = 0; t2 < 2; ++t2) {
            a[t2][0] = abuf[k % PF][t2][0];
            a[t2][1] = abuf[k % PF][t2][1];
        }
        // prefetch A fragments for k+PF
        if (k + PF < KK) {
            #pragma unroll
            for (int t2 = 0; t2 < 2; ++t2) {
                const bf16x8* ar =
                    (const bf16x8*)(xin + (long)idxbuf[(k + PF) % DI][t2] * 64);
                abuf[k % PF][t2][0] = ar[quad];
                abuf[k % PF][t2][1] = ar[4 + quad];
            }
        }
        // prefetch indices for k+DI
        if (k + DI < KK) {
            const int* dk = dense + (long)(k + DI) * (n + 1);
            idxbuf[k % DI][0] = dk[jm[0]];
            idxbuf[k % DI][1] = dk[jm[1]];
        }
        const unsigned short* wk = wbase + (long)k * (COUT * 64);
        #pragma unroll
        for (int s = 0; s < 2; ++s) {
            #pragma unroll
            for (int t = 0; t < NT; ++t) {
                bf16x8 b = *(const bf16x8*)(wk + (t * 16 + m16) * 64 + s * 32);
                acc[0][t] = mfma16(a[0][s], b, acc[0][t]);
                acc[1][t] = mfma16(a[1][s], b, acc[1][t]);
            }
        }
    }

    #pragma unroll
    for (int t2 = 0; t2 < 2; ++t2) {
        long row = j0 + t2 * 16 + quad * 4;    // D: col=m16, row=quad*4+reg
        #pragma unroll
        for (int t = 0; t < NT; ++t) {
            #pragma unroll
            for (int r2 = 0; r2 < 4; ++r2) {
                long rr = row + r2;
                if (rr < n)
                    out[rr * COUT + colblk * (NT * 16) + t * 16 + m16] = acc[t2][t][r2];
            }
        }
    }
}

// ---------------- BN+ReLU on x2 fused with segment-max pool ----------------
__global__ void pool_kernel(const float* __restrict__ x, const float* __restrict__ stats,
                            const float* __restrict__ g, const float* __restrict__ be,
                            const int* __restrict__ seg, long n, unsigned* __restrict__ pooled) {
    long j = (long)blockIdx.x * 4 + threadIdx.y;
    if (j >= n) return;
    int c = threadIdx.x;
    float mu  = stats[c] / (float)n;
    float var = stats[64 + c] / (float)n - mu * mu;
    float rs  = rsqrtf(var + EPS);
    float v   = g[c] * (x[j * 64 + c] - mu) * rs + be[c];
    if (v < 0.f) v = 0.f;
    atomicMax(&pooled[(long)seg[j] * 64 + c], __float_as_uint(v));
}

__global__ void pooled_bf16_kernel(const unsigned* __restrict__ pooled, long np,
                                   unsigned short* __restrict__ out) {
    long j = (long)blockIdx.x * 4 + threadIdx.y;
    if (j > np) return;
    int c = threadIdx.x;
    out[j * 64 + c] = (j == np) ? (unsigned short)0
                                : f2bf(__uint_as_float(pooled[j * 64 + c]));
}

// ---------------- final BN+ReLU, in place on d_out ----------------
__global__ void bnrelu_out_kernel(float* __restrict__ x, const float* __restrict__ stats,
                                  const float* __restrict__ g, const float* __restrict__ be,
                                  long n) {
    long j = (long)blockIdx.x * 2 + threadIdx.y;
    if (j >= n) return;
    int c = threadIdx.x;  // 128
    float mu  = stats[c] / (float)n;
    float var = stats[128 + c] / (float)n - mu * mu;
    float rs  = rsqrtf(var + EPS);
    float v   = g[c] * (x[j * 128 + c] - mu) * rs + be[c];
    x[j * 128 + c] = v > 0.f ? v : 0.f;
}

extern "C" void kernel_launch(void* const* d_in, const int* in_sizes, int n_in,
                              void* d_out, int out_size, void* d_ws, size_t ws_size,
                              hipStream_t stream) {
    const float* feats = (const float*)d_in[0];
    const float* W1  = (const float*)d_in[1];
    const float* g1  = (const float*)d_in[3];
    const float* be1 = (const float*)d_in[4];
    const float* W2  = (const float*)d_in[5];
    const float* g2  = (const float*)d_in[7];
    const float* be2 = (const float*)d_in[8];
    const float* W3  = (const float*)d_in[9];
    const float* g3  = (const float*)d_in[11];
    const float* be3 = (const float*)d_in[12];
    const int* km_in   = (const int*)d_in[13];
    const int* km_out  = (const int*)d_in[14];
    const int* pool_seg = (const int*)d_in[15];
    const int* km2_in  = (const int*)d_in[16];
    const int* km2_out = (const int*)d_in[17];

    const int n  = in_sizes[0];           // 160000
    const int M  = in_sizes[13] / KK;
    const int np = out_size / 128;        // N_POOL
    const int M2 = in_sizes[16] / KK;

    // bias terms (b1/b2/b3) skipped: constant per-channel shift cancels through
    // training-mode BatchNorm exactly (mean-subtracted, variance unchanged).

    char* ws = (char*)d_ws;
    size_t off = 0;
    auto alloc = [&](size_t bytes) -> char* {
        char* p = ws + off;
        off += (bytes + 255) & ~(size_t)255;
        return p;
    };
    int* dense1 = (int*)alloc((size_t)KK * (n + 1) * 4);
    int* dense2 = (int*)alloc((size_t)KK * (np + 1) * 4);
    unsigned short* W2t = (unsigned short*)alloc((size_t)KK * 64 * 64 * 2);
    unsigned short* W3t = (unsigned short*)alloc((size_t)KK * 128 * 64 * 2);
    float* stats = (float*)alloc(4096);
    unsigned short* x1n = (unsigned short*)alloc((size_t)(n + 1) * 64 * 2);
    float* bufA = (float*)alloc((size_t)n * 64 * 4);
    unsigned* pooled = (unsigned*)alloc((size_t)np * 64 * 4);
    unsigned short* xpn = (unsigned short*)alloc((size_t)(np + 1) * 64 * 2);
    float* x3 = (float*)d_out;
    if (off > ws_size) return;

    float* stats1 = stats;
    float* stats2 = stats + 128;
    float* stats3 = stats + 256;

    hipMemsetAsync(stats, 0, 4096, stream);
    hipMemsetAsync(pooled, 0, (size_t)np * 64 * 4, stream);

    {
        long t1 = (long)KK * (n + 1);
        fill_i32<<<(int)((t1 + 255) / 256), 256, 0, stream>>>(dense1, t1, n);
        long t2 = (long)KK * (np + 1);
        fill_i32<<<(int)((t2 + 255) / 256), 256, 0, stream>>>(dense2, t2, np);
        long e1 = (long)KK * M;
        invert_map<<<(int)((e1 + 255) / 256), 256, 0, stream>>>(km_in, km_out, dense1, M, n);
        long e2 = (long)KK * M2;
        invert_map<<<(int)((e2 + 255) / 256), 256, 0, stream>>>(km2_in, km2_out, dense2, M2, np);
    }
    {
        long t2 = (long)KK * 64 * 64;
        wt_bf16<<<(int)((t2 + 255) / 256), 256, 0, stream>>>(W2, W2t, 64, 64);
        long t3 = (long)KK * 64 * 128;
        wt_bf16<<<(int)((t3 + 255) / 256), 256, 0, stream>>>(W3, W3t, 64, 128);
    }

    auto swgrid = [](long nblk) { return (int)(((nblk + 7) / 8) * 8); };

    dim3 b64x4(64, 4);
    // layer 1
    conv1_kernel<<<(n + 3) / 4, b64x4, 0, stream>>>(feats, W1, dense1, n, bufA);
    stats_kernel<64><<<1024, 256, 0, stream>>>(bufA, n, stats1);
    bnrelu_bf16_kernel<<<(n + 1 + 3) / 4, b64x4, 0, stream>>>(bufA, stats1, g1, be1, n, x1n);
    // layer 2 (MFMA): 32 rows/wave, CB=1
    {
        long waves = (n + 31) / 32;
        conv_mfma<4, 1><<<swgrid((waves + 3) / 4), 256, 0, stream>>>(x1n, W2t, dense1, bufA, n);
    }
    stats_kernel<64><<<1024, 256, 0, stream>>>(bufA, n, stats2);
    pool_kernel<<<(n + 3) / 4, b64x4, 0, stream>>>(bufA, stats2, g2, be2, pool_seg, n, pooled);
    pooled_bf16_kernel<<<(np + 1 + 3) / 4, b64x4, 0, stream>>>(pooled, np, xpn);
    // layer 3 (MFMA): 32 rows/wave, 2 column blocks of 64
    {
        long waves = ((np + 31) / 32) * 2;
        conv_mfma<4, 2><<<swgrid((waves + 3) / 4), 256, 0, stream>>>(xpn, W3t, dense2, x3, np);
    }
    stats_kernel<128><<<1024, 256, 0, stream>>>(x3, np, stats3);
    bnrelu_out_kernel<<<(np + 1) / 2, dim3(128, 2), 0, stream>>>(x3, stats3, g3, be3, np);
}

// Round 3
// 812.550 us; speedup vs baseline: 1.2555x; 1.0752x over previous
//
#include <hip/hip_runtime.h>

#define EPS 1e-5f
#define KK 27

typedef __bf16 bf16x8 __attribute__((ext_vector_type(8)));
typedef float f32x4 __attribute__((ext_vector_type(4)));

__device__ __forceinline__ unsigned short f2bf(float f) {
    union { float f; unsigned u; } v; v.f = f;
    unsigned r = v.u + 0x7fffu + ((v.u >> 16) & 1u);  // round-to-nearest-even
    return (unsigned short)(r >> 16);
}

__device__ __forceinline__ f32x4 mfma16(bf16x8 a, bf16x8 b, f32x4 c) {
    return __builtin_amdgcn_mfma_f32_16x16x32_bf16(a, b, c, 0, 0, 0);
}

// ---------------- map inversion ----------------
__global__ void fill_i32(int* __restrict__ p, long tot, int val) {
    long i = (long)blockIdx.x * blockDim.x + threadIdx.x;
    if (i < tot) p[i] = val;
}

__global__ void invert_map(const int* __restrict__ km_in, const int* __restrict__ km_out,
                           int* __restrict__ dense, int M, int nrows) {
    long i = (long)blockIdx.x * blockDim.x + threadIdx.x;
    if (i >= (long)KK * M) return;
    int k = (int)(i / M);
    int ki = km_in[i];
    if (ki < nrows) dense[(long)k * (nrows + 1) + km_out[i]] = ki;
}

// ---------------- weight prep: W[k][ci][co] f32 -> Wt[k][co][ci] bf16 ----------------
__global__ void wt_bf16(const float* __restrict__ W, unsigned short* __restrict__ Wt,
                        int Cin, int Cout) {
    long i = (long)blockIdx.x * blockDim.x + threadIdx.x;
    long tot = (long)KK * Cin * Cout;
    if (i >= tot) return;
    int k  = (int)(i / (Cin * Cout));
    int r  = (int)(i % (Cin * Cout));
    int ci = r / Cout, co = r % Cout;
    Wt[((long)k * Cout + co) * Cin + ci] = f2bf(W[i]);
}

// ---------------- conv1: 1 -> 64 channels, f32, out-centric gather ----------------
__global__ void conv1_kernel(const float* __restrict__ feats, const float* __restrict__ W1,
                             const int* __restrict__ dense, int n, float* __restrict__ out) {
    __shared__ float w1s[KK * 64];
    int tid = threadIdx.y * 64 + threadIdx.x;
    for (int i = tid; i < KK * 64; i += 256) w1s[i] = W1[i];
    __syncthreads();
    int j = blockIdx.x * 4 + threadIdx.y;
    if (j >= n) return;
    int c = threadIdx.x;
    float f[KK];
    #pragma unroll
    for (int k = 0; k < KK; ++k) {
        int r = dense[(long)k * (n + 1) + j];
        f[k] = (r < n) ? feats[r] : 0.f;
    }
    float acc = 0.f;
    #pragma unroll
    for (int k = 0; k < KK; ++k) acc += f[k] * w1s[k * 64 + c];
    out[(long)j * 64 + c] = acc;
}

// ---------------- per-channel sum / sumsq ----------------
template <int C>
__global__ void stats_kernel(const float* __restrict__ x, long n, float* __restrict__ stats) {
    constexpr int RPB = 256 / C;
    __shared__ float ls[256], lss[256];
    int tid = threadIdx.x;
    int c = tid % C;
    long row = (long)blockIdx.x * RPB + tid / C;
    long stride = (long)gridDim.x * RPB;
    float s = 0.f, ss = 0.f;
    for (; row < n; row += stride) {
        float v = x[row * C + c];
        s += v; ss += v * v;
    }
    ls[tid] = s; lss[tid] = ss;
    __syncthreads();
    if (tid < C) {
        float S = 0.f, SS = 0.f;
        #pragma unroll
        for (int g = 0; g < RPB; ++g) { S += ls[g * C + c]; SS += lss[g * C + c]; }
        atomicAdd(&stats[c], S);
        atomicAdd(&stats[C + c], SS);
    }
}

// ---------------- BN+ReLU -> bf16 (row n written as zeros = the padded row) ----------------
__global__ void bnrelu_bf16_kernel(const float* __restrict__ x, const float* __restrict__ stats,
                                   const float* __restrict__ g, const float* __restrict__ be,
                                   long n, unsigned short* __restrict__ out) {
    long j = (long)blockIdx.x * 4 + threadIdx.y;
    if (j > n) return;
    int c = threadIdx.x;
    unsigned short v16 = 0;
    if (j < n) {
        float mu  = stats[c] / (float)n;
        float var = stats[64 + c] / (float)n - mu * mu;
        float rs  = rsqrtf(var + EPS);
        float v   = g[c] * (x[j * 64 + c] - mu) * rs + be[c];
        v16 = f2bf(v > 0.f ? v : 0.f);
    }
    out[j * 64 + c] = v16;
}

// ---------------- MFMA gather-conv, software-pipelined ----------------
// One wave = 32 output rows (2 M-tiles) x COUT=NT*16 output cols.
// xin: (n+1) x 64 bf16 (row n zeros). Wt: KK x COUT x 64 bf16. dense: KK x (n+1).
// All 27x2 gather indices loaded upfront; A-row gathers pipelined PF deep.
// MINW (min waves/EU) sized so the register allocator keeps the pipeline live:
// the R1 failure mode was launch_bounds(256) w/o MINW -> 60 VGPRs -> prefetch sunk.
template <int NT, int MINW>
__global__ __launch_bounds__(256, MINW) void conv_mfma(const unsigned short* __restrict__ xin,
                                                       const unsigned short* __restrict__ Wt,
                                                       const int* __restrict__ dense,
                                                       float* __restrict__ out, int n) {
    constexpr int COUT = NT * 16;
    constexpr int PF = 3;   // A-fragment prefetch depth
    int wave = threadIdx.x >> 6;
    int lane = threadIdx.x & 63;
    int m16 = lane & 15, quad = lane >> 4;

    long tile = (long)blockIdx.x * 4 + wave;
    long j0 = tile * 32;
    if (j0 >= n) return;

    int jm[2];
    jm[0] = (int)j0 + m16;
    jm[1] = (int)j0 + 16 + m16;
    if (jm[0] > n) jm[0] = n;   // sentinel slot: dense[k][n]==n -> zero row
    if (jm[1] > n) jm[1] = n;

    // all gather indices upfront: 54 independent coalesced loads in flight
    int idx[KK][2];
    #pragma unroll
    for (int k = 0; k < KK; ++k) {
        const int* dk = dense + (long)k * (n + 1);
        idx[k][0] = dk[jm[0]];
        idx[k][1] = dk[jm[1]];
    }

    bf16x8 abuf[PF][2][2];
    #pragma unroll
    for (int p = 0; p < PF; ++p) {
        #pragma unroll
        for (int t2 = 0; t2 < 2; ++t2) {
            const bf16x8* ar = (const bf16x8*)(xin + (long)idx[p][t2] * 64);
            abuf[p][t2][0] = ar[quad];
            abuf[p][t2][1] = ar[4 + quad];
        }
    }

    f32x4 acc[2][NT];
    #pragma unroll
    for (int t2 = 0; t2 < 2; ++t2)
        #pragma unroll
        for (int t = 0; t < NT; ++t) acc[t2][t] = (f32x4){0.f, 0.f, 0.f, 0.f};

    const unsigned short* wbase = Wt + quad * 8;

    #pragma unroll
    for (int k = 0; k < KK; ++k) {
        bf16x8 a[2][2];
        #pragma unroll
        for (int t2 = 0; t2 < 2; ++t2) {
            a[t2][0] = abuf[k % PF][t2][0];
            a[t2][1] = abuf[k % PF][t2][1];
        }
        // prefetch A fragments for k+PF into the slot just freed
        if (k + PF < KK) {
            #pragma unroll
            for (int t2 = 0; t2 < 2; ++t2) {
                const bf16x8* ar = (const bf16x8*)(xin + (long)idx[k + PF][t2] * 64);
                abuf[k % PF][t2][0] = ar[quad];
                abuf[k % PF][t2][1] = ar[4 + quad];
            }
        }
        const unsigned short* wk = wbase + (long)k * (COUT * 64);
        #pragma unroll
        for (int s = 0; s < 2; ++s) {
            #pragma unroll
            for (int t = 0; t < NT; ++t) {
                bf16x8 b = *(const bf16x8*)(wk + (t * 16 + m16) * 64 + s * 32);
                acc[0][t] = mfma16(a[0][s], b, acc[0][t]);
                acc[1][t] = mfma16(a[1][s], b, acc[1][t]);
            }
        }
    }

    #pragma unroll
    for (int t2 = 0; t2 < 2; ++t2) {
        long row = j0 + t2 * 16 + quad * 4;    // D: col=m16, row=quad*4+reg
        #pragma unroll
        for (int t = 0; t < NT; ++t) {
            #pragma unroll
            for (int r2 = 0; r2 < 4; ++r2) {
                long rr = row + r2;
                if (rr < n)
                    out[rr * COUT + t * 16 + m16] = acc[t2][t][r2];
            }
        }
    }
}

// ---------------- BN+ReLU on x2 fused with segment-max pool ----------------
__global__ void pool_kernel(const float* __restrict__ x, const float* __restrict__ stats,
                            const float* __restrict__ g, const float* __restrict__ be,
                            const int* __restrict__ seg, long n, unsigned* __restrict__ pooled) {
    long j = (long)blockIdx.x * 4 + threadIdx.y;
    if (j >= n) return;
    int c = threadIdx.x;
    float mu  = stats[c] / (float)n;
    float var = stats[64 + c] / (float)n - mu * mu;
    float rs  = rsqrtf(var + EPS);
    float v   = g[c] * (x[j * 64 + c] - mu) * rs + be[c];
    if (v < 0.f) v = 0.f;
    atomicMax(&pooled[(long)seg[j] * 64 + c], __float_as_uint(v));
}

__global__ void pooled_bf16_kernel(const unsigned* __restrict__ pooled, long np,
                                   unsigned short* __restrict__ out) {
    long j = (long)blockIdx.x * 4 + threadIdx.y;
    if (j > np) return;
    int c = threadIdx.x;
    out[j * 64 + c] = (j == np) ? (unsigned short)0
                                : f2bf(__uint_as_float(pooled[j * 64 + c]));
}

// ---------------- final BN+ReLU, in place on d_out ----------------
__global__ void bnrelu_out_kernel(float* __restrict__ x, const float* __restrict__ stats,
                                  const float* __restrict__ g, const float* __restrict__ be,
                                  long n) {
    long j = (long)blockIdx.x * 2 + threadIdx.y;
    if (j >= n) return;
    int c = threadIdx.x;  // 128
    float mu  = stats[c] / (float)n;
    float var = stats[128 + c] / (float)n - mu * mu;
    float rs  = rsqrtf(var + EPS);
    float v   = g[c] * (x[j * 128 + c] - mu) * rs + be[c];
    x[j * 128 + c] = v > 0.f ? v : 0.f;
}

extern "C" void kernel_launch(void* const* d_in, const int* in_sizes, int n_in,
                              void* d_out, int out_size, void* d_ws, size_t ws_size,
                              hipStream_t stream) {
    const float* feats = (const float*)d_in[0];
    const float* W1  = (const float*)d_in[1];
    const float* g1  = (const float*)d_in[3];
    const float* be1 = (const float*)d_in[4];
    const float* W2  = (const float*)d_in[5];
    const float* g2  = (const float*)d_in[7];
    const float* be2 = (const float*)d_in[8];
    const float* W3  = (const float*)d_in[9];
    const float* g3  = (const float*)d_in[11];
    const float* be3 = (const float*)d_in[12];
    const int* km_in   = (const int*)d_in[13];
    const int* km_out  = (const int*)d_in[14];
    const int* pool_seg = (const int*)d_in[15];
    const int* km2_in  = (const int*)d_in[16];
    const int* km2_out = (const int*)d_in[17];

    const int n  = in_sizes[0];           // 160000
    const int M  = in_sizes[13] / KK;
    const int np = out_size / 128;        // N_POOL
    const int M2 = in_sizes[16] / KK;

    // bias terms (b1/b2/b3) skipped: constant per-channel shift cancels through
    // training-mode BatchNorm exactly (mean-subtracted, variance unchanged).

    char* ws = (char*)d_ws;
    size_t off = 0;
    auto alloc = [&](size_t bytes) -> char* {
        char* p = ws + off;
        off += (bytes + 255) & ~(size_t)255;
        return p;
    };
    int* dense1 = (int*)alloc((size_t)KK * (n + 1) * 4);
    int* dense2 = (int*)alloc((size_t)KK * (np + 1) * 4);
    unsigned short* W2t = (unsigned short*)alloc((size_t)KK * 64 * 64 * 2);
    unsigned short* W3t = (unsigned short*)alloc((size_t)KK * 128 * 64 * 2);
    float* stats = (float*)alloc(4096);
    unsigned short* x1n = (unsigned short*)alloc((size_t)(n + 1) * 64 * 2);
    float* bufA = (float*)alloc((size_t)n * 64 * 4);
    unsigned* pooled = (unsigned*)alloc((size_t)np * 64 * 4);
    unsigned short* xpn = (unsigned short*)alloc((size_t)(np + 1) * 64 * 2);
    float* x3 = (float*)d_out;
    if (off > ws_size) return;

    float* stats1 = stats;
    float* stats2 = stats + 128;
    float* stats3 = stats + 256;

    hipMemsetAsync(stats, 0, 4096, stream);
    hipMemsetAsync(pooled, 0, (size_t)np * 64 * 4, stream);

    {
        long t1 = (long)KK * (n + 1);
        fill_i32<<<(int)((t1 + 255) / 256), 256, 0, stream>>>(dense1, t1, n);
        long t2 = (long)KK * (np + 1);
        fill_i32<<<(int)((t2 + 255) / 256), 256, 0, stream>>>(dense2, t2, np);
        long e1 = (long)KK * M;
        invert_map<<<(int)((e1 + 255) / 256), 256, 0, stream>>>(km_in, km_out, dense1, M, n);
        long e2 = (long)KK * M2;
        invert_map<<<(int)((e2 + 255) / 256), 256, 0, stream>>>(km2_in, km2_out, dense2, M2, np);
    }
    {
        long t2 = (long)KK * 64 * 64;
        wt_bf16<<<(int)((t2 + 255) / 256), 256, 0, stream>>>(W2, W2t, 64, 64);
        long t3 = (long)KK * 64 * 128;
        wt_bf16<<<(int)((t3 + 255) / 256), 256, 0, stream>>>(W3, W3t, 64, 128);
    }

    dim3 b64x4(64, 4);
    // layer 1
    conv1_kernel<<<(n + 3) / 4, b64x4, 0, stream>>>(feats, W1, dense1, n, bufA);
    stats_kernel<64><<<1024, 256, 0, stream>>>(bufA, n, stats1);
    bnrelu_bf16_kernel<<<(n + 1 + 3) / 4, b64x4, 0, stream>>>(bufA, stats1, g1, be1, n, x1n);
    // layer 2 (MFMA): 32 rows/wave, 64 cols
    {
        long waves = (n + 31) / 32;
        conv_mfma<4, 3><<<(int)((waves + 3) / 4), 256, 0, stream>>>(x1n, W2t, dense1, bufA, n);
    }
    stats_kernel<64><<<1024, 256, 0, stream>>>(bufA, n, stats2);
    pool_kernel<<<(n + 3) / 4, b64x4, 0, stream>>>(bufA, stats2, g2, be2, pool_seg, n, pooled);
    pooled_bf16_kernel<<<(np + 1 + 3) / 4, b64x4, 0, stream>>>(pooled, np, xpn);
    // layer 3 (MFMA): 32 rows/wave, all 128 cols per wave
    {
        long waves = (np + 31) / 32;
        conv_mfma<8, 2><<<(int)((waves + 3) / 4), 256, 0, stream>>>(xpn, W3t, dense2, x3, np);
    }
    stats_kernel<128><<<1024, 256, 0, stream>>>(x3, np, stats3);
    bnrelu_out_kernel<<<(np + 1) / 2, dim3(128, 2), 0, stream>>>(x3, stats3, g3, be3, np);
}

// Round 4
// 621.501 us; speedup vs baseline: 1.6415x; 1.3074x over previous
//
#include <hip/hip_runtime.h>

#define EPS 1e-5f
#define KK 27

typedef __bf16 bf16x8 __attribute__((ext_vector_type(8)));
typedef float f32x4 __attribute__((ext_vector_type(4)));

__device__ __forceinline__ unsigned short f2bf(float f) {
    union { float f; unsigned u; } v; v.f = f;
    unsigned r = v.u + 0x7fffu + ((v.u >> 16) & 1u);  // round-to-nearest-even
    return (unsigned short)(r >> 16);
}
__device__ __forceinline__ float bf2f(unsigned short h) {
    union { unsigned u; float f; } v; v.u = ((unsigned)h) << 16; return v.f;
}

__device__ __forceinline__ f32x4 mfma16(bf16x8 a, bf16x8 b, f32x4 c) {
    return __builtin_amdgcn_mfma_f32_16x16x32_bf16(a, b, c, 0, 0, 0);
}

// ---------------- map inversion ----------------
__global__ void fill_i32(int* __restrict__ p, long tot, int val) {
    long i = (long)blockIdx.x * blockDim.x + threadIdx.x;
    if (i < tot) p[i] = val;
}

__global__ void invert_map(const int* __restrict__ km_in, const int* __restrict__ km_out,
                           int* __restrict__ dense, int M, int nrows) {
    long i = (long)blockIdx.x * blockDim.x + threadIdx.x;
    if (i >= (long)KK * M) return;
    int k = (int)(i / M);
    int ki = km_in[i];
    if (ki < nrows) dense[(long)k * (nrows + 1) + km_out[i]] = ki;
}

// ---------------- weight prep ----------------
// W[k][ci][co] f32 -> Wt[k][co][ci] bf16
__global__ void wt_bf16(const float* __restrict__ W, unsigned short* __restrict__ Wt,
                        int Cin, int Cout) {
    long i = (long)blockIdx.x * blockDim.x + threadIdx.x;
    long tot = (long)KK * Cin * Cout;
    if (i >= tot) return;
    int k  = (int)(i / (Cin * Cout));
    int r  = (int)(i % (Cin * Cout));
    int ci = r / Cout, co = r % Cout;
    Wt[((long)k * Cout + co) * Cin + ci] = f2bf(W[i]);
}

// W1[k][0][c] f32 (27x64) -> W1t[c][kk] bf16 (64x32, kk>=27 zero)
__global__ void w1t_bf16(const float* __restrict__ W1, unsigned short* __restrict__ W1t) {
    int i = blockIdx.x * blockDim.x + threadIdx.x;  // 2048
    if (i >= 64 * 32) return;
    int c = i / 32, kk = i % 32;
    W1t[i] = (kk < KK) ? f2bf(W1[kk * 64 + c]) : (unsigned short)0;
}

// ---------------- conv1 as gather-MFMA: G[n][27(pad32)] x W1t -> bf16 raw out ----------------
// One wave = 32 output rows x 64 cols, a single K=32 MFMA step per (row-tile, col-tile).
// Lane (m16,quad) gathers its own 8 A-elements: k=quad*8+i for rows j0+m16, j0+16+m16.
__global__ __launch_bounds__(256, 2) void conv1_mfma(const float* __restrict__ feats,
                                                     const unsigned short* __restrict__ W1t,
                                                     const int* __restrict__ dense, int n,
                                                     unsigned short* __restrict__ out) {
    int wave = threadIdx.x >> 6, lane = threadIdx.x & 63;
    int m16 = lane & 15, quad = lane >> 4;
    long tile = (long)blockIdx.x * 4 + wave;
    long j0 = tile * 32;
    if (j0 >= n) return;
    int jm[2] = {(int)j0 + m16, (int)j0 + 16 + m16};
    if (jm[0] > n) jm[0] = n;    // dense[k][n]==n sentinel
    if (jm[1] > n) jm[1] = n;

    // indices first (independent), then gathers (feats is 640KB -> L2-resident)
    int idx[2][8];
    #pragma unroll
    for (int i = 0; i < 8; ++i) {
        int kk = quad * 8 + i;
        bool kv = (kk < KK);
        #pragma unroll
        for (int t2 = 0; t2 < 2; ++t2)
            idx[t2][i] = kv ? dense[(long)kk * (n + 1) + jm[t2]] : n;
    }
    float f[2][8];
    #pragma unroll
    for (int i = 0; i < 8; ++i)
        #pragma unroll
        for (int t2 = 0; t2 < 2; ++t2) {
            int r = idx[t2][i];
            f[t2][i] = (r < n) ? feats[r] : 0.f;
        }

    union { bf16x8 v; unsigned short s[8]; } a[2];
    #pragma unroll
    for (int t2 = 0; t2 < 2; ++t2)
        #pragma unroll
        for (int i = 0; i < 8; ++i) a[t2].s[i] = f2bf(f[t2][i]);

    f32x4 acc[2][4];
    #pragma unroll
    for (int t2 = 0; t2 < 2; ++t2)
        #pragma unroll
        for (int t = 0; t < 4; ++t) acc[t2][t] = (f32x4){0.f, 0.f, 0.f, 0.f};

    const unsigned short* wb = W1t + quad * 8;
    #pragma unroll
    for (int t = 0; t < 4; ++t) {
        bf16x8 b = *(const bf16x8*)(wb + (t * 16 + m16) * 32);
        acc[0][t] = mfma16(a[0].v, b, acc[0][t]);
        acc[1][t] = mfma16(a[1].v, b, acc[1][t]);
    }

    #pragma unroll
    for (int t2 = 0; t2 < 2; ++t2) {
        long row = j0 + t2 * 16 + quad * 4;   // D: col=m16, row=quad*4+reg
        #pragma unroll
        for (int t = 0; t < 4; ++t)
            #pragma unroll
            for (int r2 = 0; r2 < 4; ++r2) {
                long rr = row + r2;
                if (rr < n) out[rr * 64 + t * 16 + m16] = f2bf(acc[t2][t][r2]);
            }
    }
}

// ---------------- per-channel sum / sumsq over bf16 ----------------
template <int C>
__global__ void stats_bf16_kernel(const unsigned short* __restrict__ x, long n,
                                  float* __restrict__ stats) {
    constexpr int RPB = 256 / C;
    __shared__ float ls[256], lss[256];
    int tid = threadIdx.x;
    int c = tid % C;
    long row = (long)blockIdx.x * RPB + tid / C;
    long stride = (long)gridDim.x * RPB;
    float s = 0.f, ss = 0.f;
    for (; row < n; row += stride) {
        float v = bf2f(x[row * C + c]);
        s += v; ss += v * v;
    }
    ls[tid] = s; lss[tid] = ss;
    __syncthreads();
    if (tid < C) {
        float S = 0.f, SS = 0.f;
        #pragma unroll
        for (int g = 0; g < RPB; ++g) { S += ls[g * C + c]; SS += lss[g * C + c]; }
        atomicAdd(&stats[c], S);
        atomicAdd(&stats[C + c], SS);
    }
}

template <int C>
__global__ void stats_kernel(const float* __restrict__ x, long n, float* __restrict__ stats) {
    constexpr int RPB = 256 / C;
    __shared__ float ls[256], lss[256];
    int tid = threadIdx.x;
    int c = tid % C;
    long row = (long)blockIdx.x * RPB + tid / C;
    long stride = (long)gridDim.x * RPB;
    float s = 0.f, ss = 0.f;
    for (; row < n; row += stride) {
        float v = x[row * C + c];
        s += v; ss += v * v;
    }
    ls[tid] = s; lss[tid] = ss;
    __syncthreads();
    if (tid < C) {
        float S = 0.f, SS = 0.f;
        #pragma unroll
        for (int g = 0; g < RPB; ++g) { S += ls[g * C + c]; SS += lss[g * C + c]; }
        atomicAdd(&stats[c], S);
        atomicAdd(&stats[C + c], SS);
    }
}

// ---------------- BN+ReLU in place on bf16 (row n zeroed = padded zero row) ----------------
__global__ void bnrelu_inplace_kernel(unsigned short* __restrict__ x,
                                      const float* __restrict__ stats,
                                      const float* __restrict__ g, const float* __restrict__ be,
                                      long n) {
    long j = (long)blockIdx.x * 4 + threadIdx.y;
    if (j > n) return;
    int c = threadIdx.x;
    unsigned short v16 = 0;
    if (j < n) {
        float mu  = stats[c] / (float)n;
        float var = stats[64 + c] / (float)n - mu * mu;
        float rs  = rsqrtf(var + EPS);
        float v   = g[c] * (bf2f(x[j * 64 + c]) - mu) * rs + be[c];
        v16 = f2bf(v > 0.f ? v : 0.f);
    }
    x[j * 64 + c] = v16;
}

// ---------------- MFMA gather-conv, software-pipelined ----------------
// One wave = 32 output rows x COUT=NT*16 cols. All 27x2 indices upfront,
// A-row gathers pipelined PF deep. BF16OUT selects output dtype.
template <int NT, int MINW, bool BF16OUT>
__global__ __launch_bounds__(256, MINW) void conv_mfma(const unsigned short* __restrict__ xin,
                                                       const unsigned short* __restrict__ Wt,
                                                       const int* __restrict__ dense,
                                                       void* __restrict__ outv, int n) {
    constexpr int COUT = NT * 16;
    constexpr int PF = 3;
    int wave = threadIdx.x >> 6;
    int lane = threadIdx.x & 63;
    int m16 = lane & 15, quad = lane >> 4;

    long tile = (long)blockIdx.x * 4 + wave;
    long j0 = tile * 32;
    if (j0 >= n) return;

    int jm[2];
    jm[0] = (int)j0 + m16;
    jm[1] = (int)j0 + 16 + m16;
    if (jm[0] > n) jm[0] = n;
    if (jm[1] > n) jm[1] = n;

    int idx[KK][2];
    #pragma unroll
    for (int k = 0; k < KK; ++k) {
        const int* dk = dense + (long)k * (n + 1);
        idx[k][0] = dk[jm[0]];
        idx[k][1] = dk[jm[1]];
    }

    bf16x8 abuf[PF][2][2];
    #pragma unroll
    for (int p = 0; p < PF; ++p)
        #pragma unroll
        for (int t2 = 0; t2 < 2; ++t2) {
            const bf16x8* ar = (const bf16x8*)(xin + (long)idx[p][t2] * 64);
            abuf[p][t2][0] = ar[quad];
            abuf[p][t2][1] = ar[4 + quad];
        }

    f32x4 acc[2][NT];
    #pragma unroll
    for (int t2 = 0; t2 < 2; ++t2)
        #pragma unroll
        for (int t = 0; t < NT; ++t) acc[t2][t] = (f32x4){0.f, 0.f, 0.f, 0.f};

    const unsigned short* wbase = Wt + quad * 8;

    #pragma unroll
    for (int k = 0; k < KK; ++k) {
        bf16x8 a[2][2];
        #pragma unroll
        for (int t2 = 0; t2 < 2; ++t2) {
            a[t2][0] = abuf[k % PF][t2][0];
            a[t2][1] = abuf[k % PF][t2][1];
        }
        if (k + PF < KK) {
            #pragma unroll
            for (int t2 = 0; t2 < 2; ++t2) {
                const bf16x8* ar = (const bf16x8*)(xin + (long)idx[k + PF][t2] * 64);
                abuf[k % PF][t2][0] = ar[quad];
                abuf[k % PF][t2][1] = ar[4 + quad];
            }
        }
        const unsigned short* wk = wbase + (long)k * (COUT * 64);
        #pragma unroll
        for (int s = 0; s < 2; ++s)
            #pragma unroll
            for (int t = 0; t < NT; ++t) {
                bf16x8 b = *(const bf16x8*)(wk + (t * 16 + m16) * 64 + s * 32);
                acc[0][t] = mfma16(a[0][s], b, acc[0][t]);
                acc[1][t] = mfma16(a[1][s], b, acc[1][t]);
            }
    }

    #pragma unroll
    for (int t2 = 0; t2 < 2; ++t2) {
        long row = j0 + t2 * 16 + quad * 4;
        #pragma unroll
        for (int t = 0; t < NT; ++t)
            #pragma unroll
            for (int r2 = 0; r2 < 4; ++r2) {
                long rr = row + r2;
                if (rr < n) {
                    if (BF16OUT)
                        ((unsigned short*)outv)[rr * COUT + t * 16 + m16] = f2bf(acc[t2][t][r2]);
                    else
                        ((float*)outv)[rr * COUT + t * 16 + m16] = acc[t2][t][r2];
                }
            }
    }
}

// ---------------- BN+ReLU on bf16 x2 fused with segment-max pool ----------------
__global__ void pool_kernel(const unsigned short* __restrict__ x, const float* __restrict__ stats,
                            const float* __restrict__ g, const float* __restrict__ be,
                            const int* __restrict__ seg, long n, unsigned* __restrict__ pooled) {
    long j = (long)blockIdx.x * 4 + threadIdx.y;
    if (j >= n) return;
    int c = threadIdx.x;
    float mu  = stats[c] / (float)n;
    float var = stats[64 + c] / (float)n - mu * mu;
    float rs  = rsqrtf(var + EPS);
    float v   = g[c] * (bf2f(x[j * 64 + c]) - mu) * rs + be[c];
    if (v < 0.f) v = 0.f;
    atomicMax(&pooled[(long)seg[j] * 64 + c], __float_as_uint(v));
}

__global__ void pooled_bf16_kernel(const unsigned* __restrict__ pooled, long np,
                                   unsigned short* __restrict__ out) {
    long j = (long)blockIdx.x * 4 + threadIdx.y;
    if (j > np) return;
    int c = threadIdx.x;
    out[j * 64 + c] = (j == np) ? (unsigned short)0
                                : f2bf(__uint_as_float(pooled[j * 64 + c]));
}

// ---------------- final BN+ReLU, in place on d_out ----------------
__global__ void bnrelu_out_kernel(float* __restrict__ x, const float* __restrict__ stats,
                                  const float* __restrict__ g, const float* __restrict__ be,
                                  long n) {
    long j = (long)blockIdx.x * 2 + threadIdx.y;
    if (j >= n) return;
    int c = threadIdx.x;  // 128
    float mu  = stats[c] / (float)n;
    float var = stats[128 + c] / (float)n - mu * mu;
    float rs  = rsqrtf(var + EPS);
    float v   = g[c] * (x[j * 128 + c] - mu) * rs + be[c];
    x[j * 128 + c] = v > 0.f ? v : 0.f;
}

extern "C" void kernel_launch(void* const* d_in, const int* in_sizes, int n_in,
                              void* d_out, int out_size, void* d_ws, size_t ws_size,
                              hipStream_t stream) {
    const float* feats = (const float*)d_in[0];
    const float* W1  = (const float*)d_in[1];
    const float* g1  = (const float*)d_in[3];
    const float* be1 = (const float*)d_in[4];
    const float* W2  = (const float*)d_in[5];
    const float* g2  = (const float*)d_in[7];
    const float* be2 = (const float*)d_in[8];
    const float* W3  = (const float*)d_in[9];
    const float* g3  = (const float*)d_in[11];
    const float* be3 = (const float*)d_in[12];
    const int* km_in   = (const int*)d_in[13];
    const int* km_out  = (const int*)d_in[14];
    const int* pool_seg = (const int*)d_in[15];
    const int* km2_in  = (const int*)d_in[16];
    const int* km2_out = (const int*)d_in[17];

    const int n  = in_sizes[0];           // 160000
    const int M  = in_sizes[13] / KK;
    const int np = out_size / 128;        // N_POOL
    const int M2 = in_sizes[16] / KK;

    // bias terms (b1/b2/b3) skipped: constant per-channel shift cancels through
    // training-mode BatchNorm exactly (mean-subtracted, variance unchanged).

    char* ws = (char*)d_ws;
    size_t off = 0;
    auto alloc = [&](size_t bytes) -> char* {
        char* p = ws + off;
        off += (bytes + 255) & ~(size_t)255;
        return p;
    };
    int* dense1 = (int*)alloc((size_t)KK * (n + 1) * 4);
    int* dense2 = (int*)alloc((size_t)KK * (np + 1) * 4);
    unsigned short* W1t = (unsigned short*)alloc(64 * 32 * 2);
    unsigned short* W2t = (unsigned short*)alloc((size_t)KK * 64 * 64 * 2);
    unsigned short* W3t = (unsigned short*)alloc((size_t)KK * 128 * 64 * 2);
    float* stats = (float*)alloc(4096);
    unsigned short* x1n = (unsigned short*)alloc((size_t)(n + 1) * 64 * 2);  // raw, then BN'd in place
    unsigned short* x2r = (unsigned short*)alloc((size_t)n * 64 * 2);        // conv2 raw bf16
    unsigned* pooled = (unsigned*)alloc((size_t)np * 64 * 4);
    unsigned short* xpn = (unsigned short*)alloc((size_t)(np + 1) * 64 * 2);
    float* x3 = (float*)d_out;
    if (off > ws_size) return;

    float* stats1 = stats;
    float* stats2 = stats + 128;
    float* stats3 = stats + 256;

    hipMemsetAsync(stats, 0, 4096, stream);
    hipMemsetAsync(pooled, 0, (size_t)np * 64 * 4, stream);

    {
        long t1 = (long)KK * (n + 1);
        fill_i32<<<(int)((t1 + 255) / 256), 256, 0, stream>>>(dense1, t1, n);
        long t2 = (long)KK * (np + 1);
        fill_i32<<<(int)((t2 + 255) / 256), 256, 0, stream>>>(dense2, t2, np);
        long e1 = (long)KK * M;
        invert_map<<<(int)((e1 + 255) / 256), 256, 0, stream>>>(km_in, km_out, dense1, M, n);
        long e2 = (long)KK * M2;
        invert_map<<<(int)((e2 + 255) / 256), 256, 0, stream>>>(km2_in, km2_out, dense2, M2, np);
    }
    {
        w1t_bf16<<<8, 256, 0, stream>>>(W1, W1t);
        long t2 = (long)KK * 64 * 64;
        wt_bf16<<<(int)((t2 + 255) / 256), 256, 0, stream>>>(W2, W2t, 64, 64);
        long t3 = (long)KK * 64 * 128;
        wt_bf16<<<(int)((t3 + 255) / 256), 256, 0, stream>>>(W3, W3t, 64, 128);
    }

    dim3 b64x4(64, 4);
    // layer 1: gather-MFMA, bf16 raw out
    {
        long waves = (n + 31) / 32;
        conv1_mfma<<<(int)((waves + 3) / 4), 256, 0, stream>>>(feats, W1t, dense1, n, x1n);
    }
    stats_bf16_kernel<64><<<1024, 256, 0, stream>>>(x1n, n, stats1);
    bnrelu_inplace_kernel<<<(n + 1 + 3) / 4, b64x4, 0, stream>>>(x1n, stats1, g1, be1, n);
    // layer 2 (MFMA): 32 rows/wave, 64 cols, bf16 out
    {
        long waves = (n + 31) / 32;
        conv_mfma<4, 3, true><<<(int)((waves + 3) / 4), 256, 0, stream>>>(x1n, W2t, dense1, x2r, n);
    }
    stats_bf16_kernel<64><<<1024, 256, 0, stream>>>(x2r, n, stats2);
    pool_kernel<<<(n + 3) / 4, b64x4, 0, stream>>>(x2r, stats2, g2, be2, pool_seg, n, pooled);
    pooled_bf16_kernel<<<(np + 1 + 3) / 4, b64x4, 0, stream>>>(pooled, np, xpn);
    // layer 3 (MFMA): 32 rows/wave, all 128 cols, f32 out into d_out
    {
        long waves = (np + 31) / 32;
        conv_mfma<8, 2, false><<<(int)((waves + 3) / 4), 256, 0, stream>>>(xpn, W3t, dense2, x3, np);
    }
    stats_kernel<128><<<1024, 256, 0, stream>>>(x3, np, stats3);
    bnrelu_out_kernel<<<(np + 1) / 2, dim3(128, 2), 0, stream>>>(x3, stats3, g3, be3, np);
}